// Round 10
// baseline (194.630 us; speedup 1.0000x reference)
//
#include <hip/hip_runtime.h>
#include <cmath>
#include <cstdint>
#include <cstring>

// ---------------------------------------------------------------------------
// eps = jax.random.normal(jax.random.key(42), (4,4)) reproduced on HOST.
// (verified PASS in earlier rounds): counter (0,e), XOR-fold the 2x32
// outputs; bits>>9|0x3f800000 -> [1,2); affine to [nextafter(-1,0), 1);
// sqrt(2)*erfinv.
// ---------------------------------------------------------------------------

static inline uint32_t rotl32(uint32_t v, int r) { return (v << r) | (v >> (32 - r)); }

static void threefry2x32_42(uint32_t x0, uint32_t x1, uint32_t& o0, uint32_t& o1) {
    const uint32_t k0 = 0u, k1 = 42u;
    const uint32_t ks[3] = { k0, k1, k0 ^ k1 ^ 0x1BD11BDAu };
    static const int R[8] = { 13, 15, 26, 6, 17, 29, 16, 24 };
    x0 += ks[0];
    x1 += ks[1];
    for (int g = 1; g <= 5; ++g) {
        const int* rr = &R[((g - 1) & 1) * 4];
        for (int j = 0; j < 4; ++j) {
            x0 += x1;
            x1 = rotl32(x1, rr[j]);
            x1 ^= x0;
        }
        x0 += ks[g % 3];
        x1 += ks[(g + 1) % 3] + (uint32_t)g;
    }
    o0 = x0;
    o1 = x1;
}

static double erfinv_d(double x) {
    float xf = (float)x;
    float w = -logf((1.0f - xf) * (1.0f + xf));
    float p;
    if (w < 5.0f) {
        w -= 2.5f;
        p = 2.81022636e-08f;
        p = fmaf(p, w, 3.43273939e-07f);
        p = fmaf(p, w, -3.5233877e-06f);
        p = fmaf(p, w, -4.39150654e-06f);
        p = fmaf(p, w, 0.00021858087f);
        p = fmaf(p, w, -0.00125372503f);
        p = fmaf(p, w, -0.00417768164f);
        p = fmaf(p, w, 0.246640727f);
        p = fmaf(p, w, 1.50140941f);
    } else {
        w = sqrtf(w) - 3.0f;
        p = -0.000200214257f;
        p = fmaf(p, w, 0.000100950558f);
        p = fmaf(p, w, 0.00134934322f);
        p = fmaf(p, w, -0.00367342844f);
        p = fmaf(p, w, 0.00573950773f);
        p = fmaf(p, w, -0.0076224613f);
        p = fmaf(p, w, 0.00943887047f);
        p = fmaf(p, w, 1.00167406f);
        p = fmaf(p, w, 2.83297682f);
    }
    double y = (double)(p * xf);
    const double c = 1.1283791670955126;
    for (int it = 0; it < 3; ++it) {
        double err = erf(y) - x;
        y -= err / (c * exp(-y * y));
    }
    return y;
}

struct EpsT { float e[16]; };

static void compute_eps(float* e) {
    const float lo = -0.99999994f;
    for (int i = 0; i < 16; ++i) {
        uint32_t a, b;
        threefry2x32_42(0u, (uint32_t)i, a, b);
        uint32_t bits = a ^ b;
        uint32_t fb = (bits >> 9) | 0x3f800000u;
        float f;
        memcpy(&f, &fb, 4);
        float u = f - 1.0f;
        float v = u * 2.0f + lo;
        if (v < lo) v = lo;
        e[i] = (float)(sqrt(2.0) * erfinv_d((double)v));
    }
}

// ---------------------------------------------------------------------------
// MFMA chain via K-permutation (layouts verified end-to-end):
//   C/D: lane (hv=lane>>5, n=lane&31), reg r -> D[row][n], row=(r&3)+8*(r>>2)+4hv
//   A:   lane (hv, m=lane&31), elem j  -> A[m][k_slot=8hv+j]
//   B:   lane (hv, n=lane&31), elem j  -> B[k_slot=8hv+j][n]
// L2/L3 relabel K with sigma(16q+8hv+j)=16q+4hv+8*(j>>2)+(j&3) so reg r of the
// previous C/D is exactly elem j=r&7 of B-fragment q=r>>3 (no cross-lane).
// W3 duplicated into rows 4-7 so both halves hold f=0..3 in regs 0-3.
//
// Round-10 (chain-split across waves): rounds 7-9 established the bind:
// 2-chain ILP needs ~150 unified regs, 4 waves/SIMD needs <=128 — impossible
// while each wave carries all 4 column-chains + full tile state. Split: each
// tile is served by TWO waves; role r=wid&1 computes chains {2r,2r+1} only.
//  * L1 K-permutation pi_r(8hv+j): elems 0-3 <- z cols {8r+4hv..+3} (= this
//    lane's OWN passthrough/output cols!), elems 4-7 <- complementary block.
//    pi preserves k&3 -> SGPR mask-AND pattern unchanged. W1 rows via pi.
//  * lane (hv,n) keeps chain c=2r+hv (regs 0-3 via W3 dup), writes one 16B
//    chunk out[n][4c..4c+3]; sibling wave (same block -> same L2) covers rest.
//  * per wave: 10 MFMAs, 2 fully interleaved chains, ~90 persistent regs,
//    peak ~125 -> launch_bounds(256,4): 4 waves/SIMD x 2 ILP = 8 hiding cap.
// ---------------------------------------------------------------------------

typedef _Float16 half8 __attribute__((ext_vector_type(8)));
typedef __fp16  fp16x2 __attribute__((ext_vector_type(2)));
typedef __fp16  fp16x4 __attribute__((ext_vector_type(4)));
typedef __fp16  fp16x8 __attribute__((ext_vector_type(8)));
typedef uint32_t uint32x4 __attribute__((ext_vector_type(4)));
typedef float floatx4 __attribute__((ext_vector_type(4)));
typedef float floatx16 __attribute__((ext_vector_type(16)));

// f32->f16 (RTZ, packed) then packed relu (v_pk_max_f16); pure register code.
static __device__ inline half8 pack8_relu(float a0, float a1, float a2, float a3,
                                          float a4, float a5, float a6, float a7) {
    fp16x2 p0 = __builtin_amdgcn_cvt_pkrtz(a0, a1);
    fp16x2 p1 = __builtin_amdgcn_cvt_pkrtz(a2, a3);
    fp16x2 p2 = __builtin_amdgcn_cvt_pkrtz(a4, a5);
    fp16x2 p3 = __builtin_amdgcn_cvt_pkrtz(a6, a7);
    fp16x4 q0 = __builtin_shufflevector(p0, p1, 0, 1, 2, 3);
    fp16x4 q1 = __builtin_shufflevector(p2, p3, 0, 1, 2, 3);
    fp16x8 r  = __builtin_shufflevector(q0, q1, 0, 1, 2, 3, 4, 5, 6, 7);
    const fp16x8 z8 = (fp16x8)0;
    r = __builtin_elementwise_max(r, z8);   // 4x v_pk_max_f16
    return __builtin_bit_cast(half8, r);
}

__global__ __launch_bounds__(256, 4) void scm_mfma(
    const float* __restrict__ z,
    const float* __restrict__ W1, const float* __restrict__ b1,
    const float* __restrict__ W2, const float* __restrict__ b2,
    const float* __restrict__ W3, const float* __restrict__ b3,
    const int* __restrict__ mask,
    float* __restrict__ out, EpsT ep, int B)
{
    const int lane = threadIdx.x & 63;
    const int hv   = lane >> 5;          // wave half
    const int n    = lane & 31;          // batch row in tile / m index
    const int wid  = blockIdx.x * (blockDim.x >> 6) + (threadIdx.x >> 6);
    const int nw   = gridDim.x * (blockDim.x >> 6);
    const int rl   = wid & 1;            // wave role: chains {2rl, 2rl+1}
    const int T    = B >> 5;             // 32-row tiles
    const int ts   = nw >> 1;            // tile stride (2 waves per tile)

    // ---- mask -> SGPRs (wave-uniform) ----
    int mku[16];
#pragma unroll
    for (int t = 0; t < 16; ++t) mku[t] = __builtin_amdgcn_readfirstlane(mask[t]);
    int cond[4];
    uint32_t M01[4], M23[4];             // uniform -> SALU/SGPR
#pragma unroll
    for (int i = 0; i < 4; ++i) {
        cond[i] = mku[i] | mku[4 + i] | mku[8 + i] | mku[12 + i];
        M01[i] = (mku[i]      ? 0x0000FFFFu : 0u) | (mku[4 + i]  ? 0xFFFF0000u : 0u);
        M23[i] = (mku[8 + i]  ? 0x0000FFFFu : 0u) | (mku[12 + i] ? 0xFFFF0000u : 0u);
    }
    // this wave's two chains (uniform selects)
    const int      condA = rl ? cond[2] : cond[0];
    const int      condB = rl ? cond[3] : cond[1];
    const uint32_t M01A  = rl ? M01[2] : M01[0], M23A = rl ? M23[2] : M23[0];
    const uint32_t M01B  = rl ? M01[3] : M01[1], M23B = rl ? M23[3] : M23[1];

    // ---- L1 K-permutation: elems 0-3 <- cols base0..base0+3 (own cols),
    //      elems 4-7 <- complementary 4-block (base0+8 mod 16) ----
    const int base0 = 8 * rl + 4 * hv;
    const int base1 = (base0 + 8) & 15;

    // ---- weight fragments (f16), built once per wave ----
    half8 w1, w2f[2], w3f[2];
#pragma unroll
    for (int j = 0; j < 4; ++j) {
        w1[j]     = (_Float16)W1[(base0 + j) * 32 + n];
        w1[4 + j] = (_Float16)W1[(base1 + j) * 32 + n];
    }
    const uint32x4 w1u = __builtin_bit_cast(uint32x4, w1);
    // pi preserves k&3 -> elems (0,1)/(4,5) carry f=0,1 and (2,3)/(6,7) f=2,3
    uint32x4 wmA, wmB;
    wmA.x = w1u.x & M01A; wmA.y = w1u.y & M23A; wmA.z = w1u.z & M01A; wmA.w = w1u.w & M23A;
    wmB.x = w1u.x & M01B; wmB.y = w1u.y & M23B; wmB.z = w1u.z & M01B; wmB.w = w1u.w & M23B;
    const half8 w1mA = __builtin_bit_cast(half8, wmA);
    const half8 w1mB = __builtin_bit_cast(half8, wmB);
#pragma unroll
    for (int q = 0; q < 2; ++q)
#pragma unroll
        for (int j = 0; j < 8; ++j) {
            const int row = 16 * q + 4 * hv + 8 * (j >> 2) + (j & 3);  // sigma(k)
            w2f[q][j] = (_Float16)W2[row * 32 + n];
            w3f[q][j] = (n < 8) ? (_Float16)W3[row * 4 + (n & 3)] : (_Float16)0.f;
        }

    // ---- biases in C/D layout (consumed directly as MFMA C operands) ----
    floatx16 b1v, b2v;
#pragma unroll
    for (int r = 0; r < 16; ++r) {
        const int h = (r & 3) + 8 * (r >> 2) + 4 * hv;
        b1v[r] = b1[h];
        b2v[r] = b2[h];
    }
    // lane keeps chain c = 2rl+hv; eb[f] = b3[f] + eps[c][f] - b2v[f]
    // (b2v is the L3 C-init; rows >= 8 never read -> exact cancel).
    // eps via compile-time indices + uniform/cndmask selects (no dyn index).
    float eb[4];
#pragma unroll
    for (int f = 0; f < 4; ++f) {
        const float eA = rl ? ep.e[8 + f]  : ep.e[f];       // chain 2rl
        const float eB = rl ? ep.e[12 + f] : ep.e[4 + f];   // chain 2rl+1
        eb[f] = b3[f] + (hv ? eB : eA) - b2v[f];
    }

    // ---- grid-stride tile loop with z prefetch (2 x 16B, pi offsets) ----
    int t = wid >> 1;
    floatx4 za = { 0.f, 0.f, 0.f, 0.f }, zb = za;
    if (t < T) {
        const float* zr = z + ((size_t)t * 32 + n) * 16;
        za = *reinterpret_cast<const floatx4*>(zr + base0);
        zb = *reinterpret_cast<const floatx4*>(zr + base1);
    }
    while (t < T) {
        const int tn = t + ts;
        floatx4 na = { 0.f, 0.f, 0.f, 0.f }, nb = na;
        if (tn < T) {
            const float* zr = z + ((size_t)tn * 32 + n) * 16;
            na = *reinterpret_cast<const floatx4*>(zr + base0);
            nb = *reinterpret_cast<const floatx4*>(zr + base1);
        }

        half8 bz;                                 // B-frag under pi (RNE cvt)
        bz[0] = (_Float16)za.x; bz[1] = (_Float16)za.y;
        bz[2] = (_Float16)za.z; bz[3] = (_Float16)za.w;
        bz[4] = (_Float16)zb.x; bz[5] = (_Float16)zb.y;
        bz[6] = (_Float16)zb.z; bz[7] = (_Float16)zb.w;

        // two fully interleaved chains A (=2rl) and B (=2rl+1)
        floatx16 cA = __builtin_amdgcn_mfma_f32_32x32x16_f16(w1mA, bz, b1v, 0, 0, 0);
        floatx16 cB = __builtin_amdgcn_mfma_f32_32x32x16_f16(w1mB, bz, b1v, 0, 0, 0);
        half8 paA = pack8_relu(cA[0], cA[1], cA[2], cA[3], cA[4], cA[5], cA[6], cA[7]);
        half8 pbA = pack8_relu(cA[8], cA[9], cA[10], cA[11], cA[12], cA[13], cA[14], cA[15]);
        half8 paB = pack8_relu(cB[0], cB[1], cB[2], cB[3], cB[4], cB[5], cB[6], cB[7]);
        half8 pbB = pack8_relu(cB[8], cB[9], cB[10], cB[11], cB[12], cB[13], cB[14], cB[15]);
        floatx16 dA = __builtin_amdgcn_mfma_f32_32x32x16_f16(w2f[0], paA, b2v, 0, 0, 0);
        floatx16 dB = __builtin_amdgcn_mfma_f32_32x32x16_f16(w2f[0], paB, b2v, 0, 0, 0);
        dA = __builtin_amdgcn_mfma_f32_32x32x16_f16(w2f[1], pbA, dA, 0, 0, 0);
        dB = __builtin_amdgcn_mfma_f32_32x32x16_f16(w2f[1], pbB, dB, 0, 0, 0);
        half8 qaA = pack8_relu(dA[0], dA[1], dA[2], dA[3], dA[4], dA[5], dA[6], dA[7]);
        half8 qbA = pack8_relu(dA[8], dA[9], dA[10], dA[11], dA[12], dA[13], dA[14], dA[15]);
        half8 qaB = pack8_relu(dB[0], dB[1], dB[2], dB[3], dB[4], dB[5], dB[6], dB[7]);
        half8 qbB = pack8_relu(dB[8], dB[9], dB[10], dB[11], dB[12], dB[13], dB[14], dB[15]);
        floatx16 eA = __builtin_amdgcn_mfma_f32_32x32x16_f16(w3f[0], qaA, b2v, 0, 0, 0);
        floatx16 eB = __builtin_amdgcn_mfma_f32_32x32x16_f16(w3f[0], qaB, b2v, 0, 0, 0);
        eA = __builtin_amdgcn_mfma_f32_32x32x16_f16(w3f[1], qbA, eA, 0, 0, 0);
        eB = __builtin_amdgcn_mfma_f32_32x32x16_f16(w3f[1], qbB, eB, 0, 0, 0);

        // lane keeps chain c=2rl+hv; default passthrough = za (own cols)
        const bool wr = (hv ? condB : condA) != 0;
        floatx4 ov;
#pragma unroll
        for (int f = 0; f < 4; ++f) {
            const float vv = (hv ? eB[f] : eA[f]) + eb[f];
            ov[f] = wr ? vv : za[f];
        }

        // lane (hv,n) writes out[n][4c..4c+3]; sibling wave covers the rest
        *reinterpret_cast<floatx4*>(out + ((size_t)t * 32 + n) * 16 + base0) = ov;

        t = tn; za = na; zb = nb;
    }
}

extern "C" void kernel_launch(void* const* d_in, const int* in_sizes, int n_in,
                              void* d_out, int out_size, void* d_ws, size_t ws_size,
                              hipStream_t stream) {
    const float* z  = (const float*)d_in[0];
    // d_in[1] = z_int (dead code in reference)
    const float* W1 = (const float*)d_in[2];
    const float* b1 = (const float*)d_in[3];
    const float* W2 = (const float*)d_in[4];
    const float* b2 = (const float*)d_in[5];
    const float* W3 = (const float*)d_in[6];
    const float* b3 = (const float*)d_in[7];
    const int* mask = (const int*)d_in[8];
    // d_in[9] = I (dead code in reference)
    float* out = (float*)d_out;

    const int B = in_sizes[0] / 16;

    EpsT ep;
    compute_eps(ep.e);   // pure host math, deterministic, capture-safe

    // 1024 blocks x 4 waves = 4096 waves; 2 waves per tile (roles 0/1 adjacent
    // -> same block -> shared L2 for z); 16 half-tiles per wave; 4 blocks/CU.
    dim3 grid(1024), block(256);
    hipLaunchKernelGGL(scm_mfma, grid, block, 0, stream,
                       z, W1, b1, W2, b2, W3, b3, mask, out, ep, B);
}